// Round 8
// baseline (186.040 us; speedup 1.0000x reference)
//
#include <hip/hip_runtime.h>

#define DIM    256
#define NCODES 1024
#define BATCH  16
#define SEQ    2048
#define NROWS  (BATCH * SEQ)   // 32768
#define NTHR   256

typedef short short8 __attribute__((ext_vector_type(8)));
typedef float f32x4 __attribute__((ext_vector_type(4)));

__device__ __forceinline__ float wave_reduce_sum(float s) {
#pragma unroll
  for (int off = 32; off > 0; off >>= 1) s += __shfl_down(s, off, 64);
  return s;
}

// round-to-nearest-even float -> bf16 (raw short)
__device__ __forceinline__ short f2bf(float f) {
  unsigned u = __builtin_bit_cast(unsigned, f);
  u = (u + 0x7fff + ((u >> 16) & 1)) >> 16;
  return (short)u;
}
__device__ __forceinline__ float bf2f(short s) {
  unsigned u = ((unsigned)(unsigned short)s) << 16;
  return __builtin_bit_cast(float, u);
}

// ---- small prep: B pack (blocks 0..63), mask/denom (64..79) ----
// bbuf: [(g128*8+s)*1024 + ((nb8*2+reg)*4+kgl)*16 + m] short8
//   code = g128*128 + nb8*16 + m ; dims = s*32 + kgl*8 + j ; reg0=hi reg1=lo
__global__ __launch_bounds__(NTHR) void k_prep(const float* __restrict__ cb,
                                               const float* __restrict__ mask,
                                               short8* __restrict__ bbuf,
                                               float* __restrict__ cbsq,
                                               float* __restrict__ denom,
                                               float* __restrict__ lsum) {
  const int bid = blockIdx.x;
  const int t = threadIdx.x;
  __shared__ float tile[16 * 257];
  if (bid < 64) {
    // ---- prep B: 16 codes per block ----
    const int nb = bid;
    const float* src = cb + (size_t)nb * 16 * DIM;
#pragma unroll
    for (int i = 0; i < 16; ++i) tile[i * 257 + t] = src[i * DIM + t];
    __syncthreads();
#pragma unroll
    for (int it = 0; it < 4; ++it) {
      const int idx = it * NTHR + t;
      const int kg = idx >> 4;
      const int m = idx & 15;
      const int reg = kg >> 5;
      const int sk = kg & 31;
      const int sg = sk >> 2;
      const int kgl = sk & 3;
      short8 v;
#pragma unroll
      for (int j = 0; j < 8; ++j) {
        const float w = tile[m * 257 + sk * 8 + j];
        const short h = f2bf(w);
        v[j] = reg ? f2bf(w - bf2f(h)) : h;
      }
      bbuf[(size_t)((nb >> 3) * 8 + sg) * 1024 +
           (((nb & 7) * 2 + reg) * 4 + kgl) * 16 + m] = v;
    }
    if (t < 16) {
      float s2 = 0.f;
      for (int c = 0; c < DIM; ++c) { const float w = tile[t * 257 + c]; s2 = fmaf(w, w, s2); }
      cbsq[nb * 16 + t] = s2;
    }
  } else {
    // ---- mask sums + zero loss accumulators ----
    const int b = bid - 64;
    float s = 0.f;
    for (int i = t; i < SEQ; i += NTHR) s += mask[b * SEQ + i];
    s = wave_reduce_sum(s);
    __shared__ float red[NTHR / 64];
    if ((t & 63) == 0) red[t >> 6] = s;
    __syncthreads();
    if (t == 0) { denom[b] = red[0] + red[1] + red[2] + red[3]; lsum[b] = 0.f; }
  }
}

// ---- mega kernel: in-kernel A split-convert + score vs ALL 1024 codes +
//      block-local argmin + gather + straight-through + masked MSE ----
// One block per 64 rows (512 blocks). sA = 64 rows full-K hi/lo (64 KB),
// CONVERTED IN-KERNEL from feat (each row owned by exactly one block ->
// conversion happens once per element; round-0's 8x redundancy is gone).
// B-fragments load DIRECTLY from bbuf (2 MB, read by all blocks ->
// unconditionally L2/L1-resident) via coalesced 1KB/wave dwordx4 loads:
// the main K-loop has NO barriers and NO LDS staging for B -> no drain
// stalls; compiler emits its own counted vmcnt.
// MFMA chain per C element is hh,lh,hl per chunk, s ascending, identical
// operand values -> bit-exact vs all previous rounds.
__global__ __launch_bounds__(NTHR, 2) void k_mega(const short8* __restrict__ bbuf,
                                                  const float* __restrict__ cbsq,
                                                  const float* __restrict__ feat,
                                                  const float* __restrict__ cb,
                                                  const float* __restrict__ mask,
                                                  float* __restrict__ outq,
                                                  float* __restrict__ lsum) {
  __shared__ short8 sA[4096];  // 64 KB: slot = s*512 + mi*128 + reg*64 + kgl*16 + m
  __shared__ float md[256];    // merge scratch (separate, ~2.3 KB)
  __shared__ int mim[256];
  __shared__ int skid[64];
  __shared__ float red[4];
  const int t = threadIdx.x;
  const int w = t >> 6;
  const int lane = t & 63;
  const int l15 = lane & 15;
  const int quad = lane >> 4;
  const int blk = blockIdx.x;        // 512 blocks x 64 rows
  const int row0 = blk * 64;

  // ---- phase 0: convert this block's 64 rows f32 -> hi/lo bf16 into sA ----
  // item (s, mi=w, kgl=(t>>4)&3, m=t&15): same expressions as old k_prep
  // -> bit-identical hi/lo planes.
  {
    const float4* __restrict__ fsrc = (const float4*)feat;
    const int mi = w;
    const int kgl = (t >> 4) & 3;
    const int m = l15;
    const int row = row0 + mi * 16 + m;
#pragma unroll
    for (int s = 0; s < 8; ++s) {
      const size_t f4 = (size_t)row * 64 + s * 8 + kgl * 2;
      const float4 x0 = fsrc[f4];
      const float4 x1 = fsrc[f4 + 1];
      const float xs[8] = {x0.x, x0.y, x0.z, x0.w, x1.x, x1.y, x1.z, x1.w};
      short8 hi, lo;
#pragma unroll
      for (int j = 0; j < 8; ++j) {
        const short hh = f2bf(xs[j]);
        hi[j] = hh;
        lo[j] = f2bf(xs[j] - bf2f(hh));
      }
      sA[s * 512 + mi * 128 + 0 * 64 + kgl * 16 + m] = hi;   // conflict-free b128
      sA[s * 512 + mi * 128 + 1 * 64 + kgl * 16 + m] = lo;
    }
  }
  __syncthreads();   // sA ready; the ONLY barrier before the merge phase

  float best[16];
  int bidx[16];
#pragma unroll
  for (int j = 0; j < 16; ++j) { best[j] = 3.4e38f; bidx[j] = 0; }

#pragma unroll 1
  for (int cg = 0; cg < 8; ++cg) {   // 128-code groups
    f32x4 C[4][2];
#pragma unroll
    for (int mi = 0; mi < 4; ++mi)
#pragma unroll
      for (int ni = 0; ni < 2; ++ni) C[mi][ni] = (f32x4)0.f;

#pragma unroll
    for (int s = 0; s < 8; ++s) {
      // B-fragments straight from global (L2-resident), coalesced per wave
      const short8* gB = bbuf + ((size_t)cg * 8 + s) * 1024 + w * 256 + lane;
      const short8 bh0 = gB[0];
      const short8 bl0 = gB[64];
      const short8 bh1 = gB[128];
      const short8 bl1 = gB[192];
      short8 ah[4], al[4];
#pragma unroll
      for (int mi = 0; mi < 4; ++mi) {
        ah[mi] = sA[s * 512 + mi * 128 + quad * 16 + l15];
        al[mi] = sA[s * 512 + mi * 128 + 64 + quad * 16 + l15];
      }
#pragma unroll
      for (int mi = 0; mi < 4; ++mi) {
        C[mi][0] = __builtin_amdgcn_mfma_f32_16x16x32_bf16(ah[mi], bh0, C[mi][0], 0, 0, 0);
        C[mi][1] = __builtin_amdgcn_mfma_f32_16x16x32_bf16(ah[mi], bh1, C[mi][1], 0, 0, 0);
      }
#pragma unroll
      for (int mi = 0; mi < 4; ++mi) {
        C[mi][0] = __builtin_amdgcn_mfma_f32_16x16x32_bf16(al[mi], bh0, C[mi][0], 0, 0, 0);
        C[mi][1] = __builtin_amdgcn_mfma_f32_16x16x32_bf16(al[mi], bh1, C[mi][1], 0, 0, 0);
      }
#pragma unroll
      for (int mi = 0; mi < 4; ++mi) {
        C[mi][0] = __builtin_amdgcn_mfma_f32_16x16x32_bf16(ah[mi], bl0, C[mi][0], 0, 0, 0);
        C[mi][1] = __builtin_amdgcn_mfma_f32_16x16x32_bf16(ah[mi], bl1, C[mi][1], 0, 0, 0);
      }
    }

    // ---- fold this code-group into per-lane running argmin ----
    float cs[2];
#pragma unroll
    for (int ni = 0; ni < 2; ++ni) cs[ni] = cbsq[cg * 128 + w * 32 + ni * 16 + l15];
#pragma unroll
    for (int mi = 0; mi < 4; ++mi)
#pragma unroll
      for (int r = 0; r < 4; ++r) {
        const int j = mi * 4 + r;
#pragma unroll
        for (int ni = 0; ni < 2; ++ni) {
          const float d = fmaf(-2.f, C[mi][ni][r], cs[ni]);
          const int code = cg * 128 + w * 32 + ni * 16 + l15;
          if (d < best[j]) { best[j] = d; bidx[j] = code; }  // codes ascending
        }
      }
  }

  // ---- cross-lane argmin (over the 16 l15 code-columns) ----
#pragma unroll
  for (int m = 1; m <= 8; m <<= 1) {
#pragma unroll
    for (int j = 0; j < 16; ++j) {
      const float od = __shfl_xor(best[j], m, 64);
      const int oi = __shfl_xor(bidx[j], m, 64);
      if (od < best[j] || (od == best[j] && oi < bidx[j])) { best[j] = od; bidx[j] = oi; }
    }
  }

  // ---- cross-wave merge via small LDS scratch ----
  if (l15 == 0) {
#pragma unroll
    for (int mi = 0; mi < 4; ++mi)
#pragma unroll
      for (int r = 0; r < 4; ++r) {
        const int row = mi * 16 + quad * 4 + r;
        md[w * 64 + row] = best[mi * 4 + r];
        mim[w * 64 + row] = bidx[mi * 4 + r];
      }
  }
  __syncthreads();
  if (t < 64) {
    float bd = md[t];
    int bi = mim[t];
#pragma unroll
    for (int ww = 1; ww < 4; ++ww) {
      const float od = md[ww * 64 + t];
      const int oi = mim[ww * 64 + t];
      if (od < bd || (od == bd && oi < bi)) { bd = od; bi = oi; }
    }
    skid[t] = bi;
  }
  __syncthreads();

  // ---- epilogue: gather + straight-through out + masked MSE ----
  const int wv = w;
  const int dg = lane;
  const int b = row0 >> 11;
  float acc = 0.f;
#pragma unroll
  for (int i = 0; i < 16; ++i) {
    const int r = wv * 16 + i;
    const size_t row = row0 + r;
    const int k = skid[r];
    const float4 q = ((const float4*)cb)[k * (DIM / 4) + dg];
    const float4 x = ((const float4*)feat)[row * (DIM / 4) + dg];
    float4 o;
    o.x = x.x + (q.x - x.x);
    o.y = x.y + (q.y - x.y);
    o.z = x.z + (q.z - x.z);
    o.w = x.w + (q.w - x.w);
    ((float4*)outq)[row * (DIM / 4) + dg] = o;
    const float m = mask[row];
    const float dx = x.x - q.x, dy = x.y - q.y, dz = x.z - q.z, dw = x.w - q.w;
    acc = fmaf(m, dx * dx + dy * dy + dz * dz + dw * dw, acc);
  }
  acc = wave_reduce_sum(acc);
  if (lane == 0) red[wv] = acc;
  __syncthreads();
  if (t == 0) atomicAdd(&lsum[b], red[0] + red[1] + red[2] + red[3]);
}

__global__ void k_final(const float* __restrict__ lsum,
                        const float* __restrict__ denom,
                        float* __restrict__ outl) {
  const int t = threadIdx.x;
  if (t < BATCH) {
    const float v = lsum[t] / denom[t];
    outl[t] = v;          // quant_loss
    outl[BATCH + t] = v;  // commit_loss (identical in forward)
  }
}

extern "C" void kernel_launch(void* const* d_in, const int* in_sizes, int n_in,
                              void* d_out, int out_size, void* d_ws, size_t ws_size,
                              hipStream_t stream) {
  const float* feat = (const float*)d_in[0];  // [16,2048,256]
  const float* mask = (const float*)d_in[1];  // [16,2048]
  const float* cb   = (const float*)d_in[2];  // [1024,256]
  float* out = (float*)d_out;

  char* p = (char*)d_ws;
  short8* bbuf = (short8*)p;                 p += (size_t)64 * 1024 * 16;    // 1.05 MB
  float* cbsq  = (float*)p;                  p += NCODES * 4;
  float* denom = (float*)p;                  p += BATCH * 4;
  float* lsum  = (float*)p;

  k_prep<<<64 + 16, NTHR, 0, stream>>>(cb, mask, bbuf, cbsq, denom, lsum);
  k_mega<<<NROWS / 64, NTHR, 0, stream>>>(bbuf, cbsq, feat, cb, mask, out, lsum);
  k_final<<<1, 64, 0, stream>>>(lsum, denom, out + (size_t)NROWS * DIM);
}

// Round 9
// 148.946 us; speedup vs baseline: 1.2490x; 1.2490x over previous
//
#include <hip/hip_runtime.h>

#define DIM    256
#define NCODES 1024
#define BATCH  16
#define SEQ    2048
#define NROWS  (BATCH * SEQ)   // 32768
#define NTHR   256

typedef short short8 __attribute__((ext_vector_type(8)));
typedef float f32x4 __attribute__((ext_vector_type(4)));

__device__ __forceinline__ float wave_reduce_sum(float s) {
#pragma unroll
  for (int off = 32; off > 0; off >>= 1) s += __shfl_down(s, off, 64);
  return s;
}

// round-to-nearest-even float -> bf16 (raw short)
__device__ __forceinline__ short f2bf(float f) {
  unsigned u = __builtin_bit_cast(unsigned, f);
  u = (u + 0x7fff + ((u >> 16) & 1)) >> 16;
  return (short)u;
}
__device__ __forceinline__ float bf2f(short s) {
  unsigned u = ((unsigned)(unsigned short)s) << 16;
  return __builtin_bit_cast(float, u);
}

// async global -> LDS, 16B per lane. LDS dest = wave-uniform base + lane*16.
__device__ __forceinline__ void cp16(const void* g, void* l) {
  __builtin_amdgcn_global_load_lds(
      (const __attribute__((address_space(1))) unsigned*)g,
      (__attribute__((address_space(3))) unsigned*)l, 16, 0, 0);
}

// ---- small prep: B pack (blocks 0..63), mask/denom (64..79) ----
// bbuf: [(g128*8+s)*1024 + ((nb8*2+reg)*4+kgl)*16 + m] short8
//   code = g128*128 + nb8*16 + m ; dims = s*32 + kgl*8 + j ; reg0=hi reg1=lo
__global__ __launch_bounds__(NTHR) void k_prep(const float* __restrict__ cb,
                                               const float* __restrict__ mask,
                                               short8* __restrict__ bbuf,
                                               float* __restrict__ cbsq,
                                               float* __restrict__ denom,
                                               float* __restrict__ lsum) {
  const int bid = blockIdx.x;
  const int t = threadIdx.x;
  __shared__ float tile[16 * 257];
  if (bid < 64) {
    // ---- prep B: 16 codes per block ----
    const int nb = bid;
    const float* src = cb + (size_t)nb * 16 * DIM;
#pragma unroll
    for (int i = 0; i < 16; ++i) tile[i * 257 + t] = src[i * DIM + t];
    __syncthreads();
#pragma unroll
    for (int it = 0; it < 4; ++it) {
      const int idx = it * NTHR + t;
      const int kg = idx >> 4;
      const int m = idx & 15;
      const int reg = kg >> 5;
      const int sk = kg & 31;
      const int sg = sk >> 2;
      const int kgl = sk & 3;
      short8 v;
#pragma unroll
      for (int j = 0; j < 8; ++j) {
        const float w = tile[m * 257 + sk * 8 + j];
        const short h = f2bf(w);
        v[j] = reg ? f2bf(w - bf2f(h)) : h;
      }
      bbuf[(size_t)((nb >> 3) * 8 + sg) * 1024 +
           (((nb & 7) * 2 + reg) * 4 + kgl) * 16 + m] = v;
    }
    if (t < 16) {
      float s2 = 0.f;
      for (int c = 0; c < DIM; ++c) { const float w = tile[t * 257 + c]; s2 = fmaf(w, w, s2); }
      cbsq[nb * 16 + t] = s2;
    }
  } else {
    // ---- mask sums + zero loss accumulators ----
    const int b = bid - 64;
    float s = 0.f;
    for (int i = t; i < SEQ; i += NTHR) s += mask[b * SEQ + i];
    s = wave_reduce_sum(s);
    __shared__ float red[NTHR / 64];
    if ((t & 63) == 0) red[t >> 6] = s;
    __syncthreads();
    if (t == 0) { denom[b] = red[0] + red[1] + red[2] + red[3]; lsum[b] = 0.f; }
  }
}

// ---- mega kernel: in-kernel A split-convert + score vs ALL 1024 codes +
//      block-local argmin + gather + straight-through + masked MSE ----
// R7 skeleton (proven 81 us, FETCH 39.5 MB) with abuf removed:
//   phase 0: convert this block's 64 rows f32 -> hi/lo bf16 into sA (64 KB)
//            using the exact old-k_prep expressions (bit-identical planes).
//   loop:    per (cg,s): {barrier; cp16-stage 16 KB sB; barrier; 24 MFMAs}.
//            The barriers keep all blocks phase-coherent on bbuf -> bbuf
//            stays L2-resident (R8 proved removing them costs 6x FETCH).
//   tail:    cross-lane + cross-wave argmin (scratch overlaid in sB),
//            gather + straight-through + masked MSE.
// LDS = 64 KB sA + 16 KB sB = 80 KB exactly -> 2 blocks/CU.
__global__ __launch_bounds__(NTHR, 2) void k_mega(const short8* __restrict__ bbuf,
                                                  const float* __restrict__ cbsq,
                                                  const float* __restrict__ feat,
                                                  const float* __restrict__ cb,
                                                  const float* __restrict__ mask,
                                                  float* __restrict__ outq,
                                                  float* __restrict__ lsum) {
  __shared__ short8 sA[4096];  // 64 KB: slot = s*512 + mi*128 + reg*64 + kgl*16 + m
  __shared__ short8 sB[1024];  // 16 KB: one (cg,s) chunk; overlaid by merge scratch
  const int t = threadIdx.x;
  const int w = t >> 6;
  const int lane = t & 63;
  const int l15 = lane & 15;
  const int quad = lane >> 4;
  const int blk = blockIdx.x;        // 512 blocks x 64 rows
  const int row0 = blk * 64;

  // ---- phase 0: convert this block's 64 rows f32 -> hi/lo bf16 into sA ----
  {
    const float4* __restrict__ fsrc = (const float4*)feat;
    const int mi = w;
    const int kgl = quad;            // == (t>>4)&3
    const int m = l15;
    const int row = row0 + mi * 16 + m;
#pragma unroll
    for (int s = 0; s < 8; ++s) {
      const size_t f4 = (size_t)row * 64 + s * 8 + kgl * 2;
      const float4 x0 = fsrc[f4];
      const float4 x1 = fsrc[f4 + 1];
      const float xs[8] = {x0.x, x0.y, x0.z, x0.w, x1.x, x1.y, x1.z, x1.w};
      short8 hi, lo;
#pragma unroll
      for (int j = 0; j < 8; ++j) {
        const short hh = f2bf(xs[j]);
        hi[j] = hh;
        lo[j] = f2bf(xs[j] - bf2f(hh));
      }
      sA[s * 512 + mi * 128 + 0 * 64 + kgl * 16 + m] = hi;   // conflict-free b128
      sA[s * 512 + mi * 128 + 1 * 64 + kgl * 16 + m] = lo;
    }
  }

  float best[16];
  int bidx[16];
#pragma unroll
  for (int j = 0; j < 16; ++j) { best[j] = 3.4e38f; bidx[j] = 0; }

#pragma unroll 1
  for (int cg = 0; cg < 8; ++cg) {   // 128-code groups
    f32x4 C[4][2];
#pragma unroll
    for (int mi = 0; mi < 4; ++mi)
#pragma unroll
      for (int ni = 0; ni < 2; ++ni) C[mi][ni] = (f32x4)0.f;

#pragma unroll
    for (int s = 0; s < 8; ++s) {
      __syncthreads();               // prev chunk's readers done (covers phase 0 at cg=0,s=0)
      {
        const short8* gB = bbuf + ((size_t)cg * 8 + s) * 1024 + t;
        char* lB = (char*)sB + (size_t)(w * 64) * 16;
#pragma unroll
        for (int i = 0; i < 4; ++i) cp16(gB + i * 256, lB + i * 4096);
      }
      __syncthreads();               // drain staged chunk
      short8 ah[4], al[4], bh[2], bl[2];
#pragma unroll
      for (int mi = 0; mi < 4; ++mi) {
        ah[mi] = sA[s * 512 + mi * 128 + quad * 16 + l15];
        al[mi] = sA[s * 512 + mi * 128 + 64 + quad * 16 + l15];
      }
#pragma unroll
      for (int ni = 0; ni < 2; ++ni) {
        bh[ni] = sB[((w * 2 + ni) * 2 + 0) * 64 + quad * 16 + l15];
        bl[ni] = sB[((w * 2 + ni) * 2 + 1) * 64 + quad * 16 + l15];
      }
#pragma unroll
      for (int mi = 0; mi < 4; ++mi)
#pragma unroll
        for (int ni = 0; ni < 2; ++ni)
          C[mi][ni] = __builtin_amdgcn_mfma_f32_16x16x32_bf16(ah[mi], bh[ni], C[mi][ni], 0, 0, 0);
#pragma unroll
      for (int mi = 0; mi < 4; ++mi)
#pragma unroll
        for (int ni = 0; ni < 2; ++ni)
          C[mi][ni] = __builtin_amdgcn_mfma_f32_16x16x32_bf16(al[mi], bh[ni], C[mi][ni], 0, 0, 0);
#pragma unroll
      for (int mi = 0; mi < 4; ++mi)
#pragma unroll
        for (int ni = 0; ni < 2; ++ni)
          C[mi][ni] = __builtin_amdgcn_mfma_f32_16x16x32_bf16(ah[mi], bl[ni], C[mi][ni], 0, 0, 0);
    }

    // ---- fold this code-group into per-lane running argmin ----
    float cs[2];
#pragma unroll
    for (int ni = 0; ni < 2; ++ni) cs[ni] = cbsq[cg * 128 + w * 32 + ni * 16 + l15];
#pragma unroll
    for (int mi = 0; mi < 4; ++mi)
#pragma unroll
      for (int r = 0; r < 4; ++r) {
        const int j = mi * 4 + r;
#pragma unroll
        for (int ni = 0; ni < 2; ++ni) {
          const float d = fmaf(-2.f, C[mi][ni][r], cs[ni]);
          const int code = cg * 128 + w * 32 + ni * 16 + l15;
          if (d < best[j]) { best[j] = d; bidx[j] = code; }  // codes ascending
        }
      }
  }

  // ---- cross-lane argmin (over the 16 l15 code-columns) ----
#pragma unroll
  for (int m = 1; m <= 8; m <<= 1) {
#pragma unroll
    for (int j = 0; j < 16; ++j) {
      const float od = __shfl_xor(best[j], m, 64);
      const int oi = __shfl_xor(bidx[j], m, 64);
      if (od < best[j] || (od == best[j] && oi < bidx[j])) { best[j] = od; bidx[j] = oi; }
    }
  }

  // ---- cross-wave merge via LDS (overlay sB; all sB reads are done) ----
  float* md = (float*)sB;                      // [4][64]
  int* mim = (int*)((char*)sB + 1024);         // [4][64]
  int* skid = (int*)((char*)sB + 2048);        // [64]
  float* red = (float*)((char*)sB + 2304);     // [4]
  __syncthreads();                             // everyone done reading sB
  if (l15 == 0) {
#pragma unroll
    for (int mi = 0; mi < 4; ++mi)
#pragma unroll
      for (int r = 0; r < 4; ++r) {
        const int row = mi * 16 + quad * 4 + r;
        md[w * 64 + row] = best[mi * 4 + r];
        mim[w * 64 + row] = bidx[mi * 4 + r];
      }
  }
  __syncthreads();
  if (t < 64) {
    float bd = md[t];
    int bi = mim[t];
#pragma unroll
    for (int ww = 1; ww < 4; ++ww) {
      const float od = md[ww * 64 + t];
      const int oi = mim[ww * 64 + t];
      if (od < bd || (od == bd && oi < bi)) { bd = od; bi = oi; }
    }
    skid[t] = bi;
  }
  __syncthreads();

  // ---- epilogue: gather + straight-through out + masked MSE ----
  const int wv = w;
  const int dg = lane;
  const int b = row0 >> 11;
  float acc = 0.f;
#pragma unroll
  for (int i = 0; i < 16; ++i) {
    const int r = wv * 16 + i;
    const size_t row = row0 + r;
    const int k = skid[r];
    const float4 q = ((const float4*)cb)[k * (DIM / 4) + dg];
    const float4 x = ((const float4*)feat)[row * (DIM / 4) + dg];
    float4 o;
    o.x = x.x + (q.x - x.x);
    o.y = x.y + (q.y - x.y);
    o.z = x.z + (q.z - x.z);
    o.w = x.w + (q.w - x.w);
    ((float4*)outq)[row * (DIM / 4) + dg] = o;
    const float m = mask[row];
    const float dx = x.x - q.x, dy = x.y - q.y, dz = x.z - q.z, dw = x.w - q.w;
    acc = fmaf(m, dx * dx + dy * dy + dz * dz + dw * dw, acc);
  }
  acc = wave_reduce_sum(acc);
  if (lane == 0) red[wv] = acc;
  __syncthreads();
  if (t == 0) atomicAdd(&lsum[b], red[0] + red[1] + red[2] + red[3]);
}

__global__ void k_final(const float* __restrict__ lsum,
                        const float* __restrict__ denom,
                        float* __restrict__ outl) {
  const int t = threadIdx.x;
  if (t < BATCH) {
    const float v = lsum[t] / denom[t];
    outl[t] = v;          // quant_loss
    outl[BATCH + t] = v;  // commit_loss (identical in forward)
  }
}

extern "C" void kernel_launch(void* const* d_in, const int* in_sizes, int n_in,
                              void* d_out, int out_size, void* d_ws, size_t ws_size,
                              hipStream_t stream) {
  const float* feat = (const float*)d_in[0];  // [16,2048,256]
  const float* mask = (const float*)d_in[1];  // [16,2048]
  const float* cb   = (const float*)d_in[2];  // [1024,256]
  float* out = (float*)d_out;

  char* p = (char*)d_ws;
  short8* bbuf = (short8*)p;                 p += (size_t)64 * 1024 * 16;    // 1.05 MB
  float* cbsq  = (float*)p;                  p += NCODES * 4;
  float* denom = (float*)p;                  p += BATCH * 4;
  float* lsum  = (float*)p;

  k_prep<<<64 + 16, NTHR, 0, stream>>>(cb, mask, bbuf, cbsq, denom, lsum);
  k_mega<<<NROWS / 64, NTHR, 0, stream>>>(bbuf, cbsq, feat, cb, mask, out, lsum);
  k_final<<<1, 64, 0, stream>>>(lsum, denom, out + (size_t)NROWS * DIM);
}

// Round 10
// 146.887 us; speedup vs baseline: 1.2666x; 1.0140x over previous
//
#include <hip/hip_runtime.h>

#define DIM    256
#define NCODES 1024
#define BATCH  16
#define SEQ    2048
#define NROWS  (BATCH * SEQ)   // 32768
#define NTHR   256

typedef short short8 __attribute__((ext_vector_type(8)));
typedef float f32x4 __attribute__((ext_vector_type(4)));

__device__ __forceinline__ float wave_reduce_sum(float s) {
#pragma unroll
  for (int off = 32; off > 0; off >>= 1) s += __shfl_down(s, off, 64);
  return s;
}

// round-to-nearest-even float -> bf16 (raw short)
__device__ __forceinline__ short f2bf(float f) {
  unsigned u = __builtin_bit_cast(unsigned, f);
  u = (u + 0x7fff + ((u >> 16) & 1)) >> 16;
  return (short)u;
}
__device__ __forceinline__ float bf2f(short s) {
  unsigned u = ((unsigned)(unsigned short)s) << 16;
  return __builtin_bit_cast(float, u);
}

// ---- small prep: B pack (blocks 0..63), mask/denom (64..79) ----
// bbuf: [(g128*8+s)*1024 + ((nb8*2+reg)*4+kgl)*16 + m] short8
//   code = g128*128 + nb8*16 + m ; dims = s*32 + kgl*8 + j ; reg0=hi reg1=lo
__global__ __launch_bounds__(NTHR) void k_prep(const float* __restrict__ cb,
                                               const float* __restrict__ mask,
                                               short8* __restrict__ bbuf,
                                               float* __restrict__ cbsq,
                                               float* __restrict__ denom,
                                               float* __restrict__ lsum) {
  const int bid = blockIdx.x;
  const int t = threadIdx.x;
  __shared__ float tile[16 * 257];
  if (bid < 64) {
    // ---- prep B: 16 codes per block ----
    const int nb = bid;
    const float* src = cb + (size_t)nb * 16 * DIM;
#pragma unroll
    for (int i = 0; i < 16; ++i) tile[i * 257 + t] = src[i * DIM + t];
    __syncthreads();
#pragma unroll
    for (int it = 0; it < 4; ++it) {
      const int idx = it * NTHR + t;
      const int kg = idx >> 4;
      const int m = idx & 15;
      const int reg = kg >> 5;
      const int sk = kg & 31;
      const int sg = sk >> 2;
      const int kgl = sk & 3;
      short8 v;
#pragma unroll
      for (int j = 0; j < 8; ++j) {
        const float w = tile[m * 257 + sk * 8 + j];
        const short h = f2bf(w);
        v[j] = reg ? f2bf(w - bf2f(h)) : h;
      }
      bbuf[(size_t)((nb >> 3) * 8 + sg) * 1024 +
           (((nb & 7) * 2 + reg) * 4 + kgl) * 16 + m] = v;
    }
    if (t < 16) {
      float s2 = 0.f;
      for (int c = 0; c < DIM; ++c) { const float w = tile[t * 257 + c]; s2 = fmaf(w, w, s2); }
      cbsq[nb * 16 + t] = s2;
    }
  } else {
    // ---- mask sums + zero loss accumulators ----
    const int b = bid - 64;
    float s = 0.f;
    for (int i = t; i < SEQ; i += NTHR) s += mask[b * SEQ + i];
    s = wave_reduce_sum(s);
    __shared__ float red[NTHR / 64];
    if ((t & 63) == 0) red[t >> 6] = s;
    __syncthreads();
    if (t == 0) { denom[b] = red[0] + red[1] + red[2] + red[3]; lsum[b] = 0.f; }
  }
}

// ---- mega kernel: in-kernel A split-convert + score vs ALL 1024 codes +
//      block-local argmin + gather + straight-through + masked MSE ----
// R9 skeleton (proven 79 us) with T14 reg-staged B instead of cp16:
//   per phase p=cg*8+s: {barrier; ds_write regs(chunk p)->sB; barrier;
//   issue global_load chunk p+1 -> regs; ds_read A,B; 24 MFMAs}.
// Register loads don't force a vmcnt(0) drain at barriers (cp16's LDS
// write did) -> the load latency rides under the MFMA phase. Ring parity
// is static (s&1, s fully unrolled; cg stride 8 even). sB content is the
// same linear chunk copy as before -> bit-exact.
// LDS = 64 KB sA + 16 KB sB = 80 KB -> 2 blocks/CU. Blocks stay
// phase-coherent via the barriers -> bbuf (2 MB) stays L2-resident.
__global__ __launch_bounds__(NTHR, 2) void k_mega(const short8* __restrict__ bbuf,
                                                  const float* __restrict__ cbsq,
                                                  const float* __restrict__ feat,
                                                  const float* __restrict__ cb,
                                                  const float* __restrict__ mask,
                                                  float* __restrict__ outq,
                                                  float* __restrict__ lsum) {
  __shared__ short8 sA[4096];  // 64 KB: slot = s*512 + mi*128 + reg*64 + kgl*16 + m
  __shared__ short8 sB[1024];  // 16 KB: one (cg,s) chunk; overlaid by merge scratch
  const int t = threadIdx.x;
  const int w = t >> 6;
  const int lane = t & 63;
  const int l15 = lane & 15;
  const int quad = lane >> 4;
  const int blk = blockIdx.x;        // 512 blocks x 64 rows
  const int row0 = blk * 64;

  // ---- prologue: issue chunk-0 B loads (latency hides under conversion) ----
  short8 rB0[4], rB1[4];
#pragma unroll
  for (int i = 0; i < 4; ++i) rB0[i] = bbuf[i * 256 + t];

  // ---- phase 0: convert this block's 64 rows f32 -> hi/lo bf16 into sA ----
  {
    const float4* __restrict__ fsrc = (const float4*)feat;
    const int mi = w;
    const int kgl = quad;            // == (t>>4)&3
    const int m = l15;
    const int row = row0 + mi * 16 + m;
#pragma unroll
    for (int s = 0; s < 8; ++s) {
      const size_t f4 = (size_t)row * 64 + s * 8 + kgl * 2;
      const float4 x0 = fsrc[f4];
      const float4 x1 = fsrc[f4 + 1];
      const float xs[8] = {x0.x, x0.y, x0.z, x0.w, x1.x, x1.y, x1.z, x1.w};
      short8 hi, lo;
#pragma unroll
      for (int j = 0; j < 8; ++j) {
        const short hh = f2bf(xs[j]);
        hi[j] = hh;
        lo[j] = f2bf(xs[j] - bf2f(hh));
      }
      sA[s * 512 + mi * 128 + 0 * 64 + kgl * 16 + m] = hi;   // conflict-free b128
      sA[s * 512 + mi * 128 + 1 * 64 + kgl * 16 + m] = lo;
    }
  }

  float best[16];
  int bidx[16];
#pragma unroll
  for (int j = 0; j < 16; ++j) { best[j] = 3.4e38f; bidx[j] = 0; }

#pragma unroll 1
  for (int cg = 0; cg < 8; ++cg) {   // 128-code groups
    f32x4 C[4][2];
#pragma unroll
    for (int mi = 0; mi < 4; ++mi)
#pragma unroll
      for (int ni = 0; ni < 2; ++ni) C[mi][ni] = (f32x4)0.f;

#pragma unroll
    for (int s = 0; s < 8; ++s) {
      __syncthreads();               // sB readers of phase p-1 done (covers sA conv at p=0)
      // ---- write this phase's chunk (in regs) to sB: linear copy ----
      if ((s & 1) == 0) {
#pragma unroll
        for (int i = 0; i < 4; ++i) sB[i * 256 + t] = rB0[i];
      } else {
#pragma unroll
        for (int i = 0; i < 4; ++i) sB[i * 256 + t] = rB1[i];
      }
      __syncthreads();               // sB ready (lgkm drain only; no vmcnt(0))
      // ---- prefetch next chunk into the other reg buffer ----
      if (s < 7 || cg < 7) {
        const short8* gB = bbuf + ((size_t)(cg * 8 + s + 1)) * 1024 + t;
        if ((s & 1) == 0) {
#pragma unroll
          for (int i = 0; i < 4; ++i) rB1[i] = gB[i * 256];
        } else {
#pragma unroll
          for (int i = 0; i < 4; ++i) rB0[i] = gB[i * 256];
        }
      }
      // ---- compute: frags from LDS, 24 MFMAs (covers prefetch latency) ----
      short8 ah[4], al[4], bh[2], bl[2];
#pragma unroll
      for (int mi = 0; mi < 4; ++mi) {
        ah[mi] = sA[s * 512 + mi * 128 + quad * 16 + l15];
        al[mi] = sA[s * 512 + mi * 128 + 64 + quad * 16 + l15];
      }
#pragma unroll
      for (int ni = 0; ni < 2; ++ni) {
        bh[ni] = sB[((w * 2 + ni) * 2 + 0) * 64 + quad * 16 + l15];
        bl[ni] = sB[((w * 2 + ni) * 2 + 1) * 64 + quad * 16 + l15];
      }
#pragma unroll
      for (int mi = 0; mi < 4; ++mi)
#pragma unroll
        for (int ni = 0; ni < 2; ++ni)
          C[mi][ni] = __builtin_amdgcn_mfma_f32_16x16x32_bf16(ah[mi], bh[ni], C[mi][ni], 0, 0, 0);
#pragma unroll
      for (int mi = 0; mi < 4; ++mi)
#pragma unroll
        for (int ni = 0; ni < 2; ++ni)
          C[mi][ni] = __builtin_amdgcn_mfma_f32_16x16x32_bf16(al[mi], bh[ni], C[mi][ni], 0, 0, 0);
#pragma unroll
      for (int mi = 0; mi < 4; ++mi)
#pragma unroll
        for (int ni = 0; ni < 2; ++ni)
          C[mi][ni] = __builtin_amdgcn_mfma_f32_16x16x32_bf16(ah[mi], bl[ni], C[mi][ni], 0, 0, 0);
    }

    // ---- fold this code-group into per-lane running argmin ----
    float cs[2];
#pragma unroll
    for (int ni = 0; ni < 2; ++ni) cs[ni] = cbsq[cg * 128 + w * 32 + ni * 16 + l15];
#pragma unroll
    for (int mi = 0; mi < 4; ++mi)
#pragma unroll
      for (int r = 0; r < 4; ++r) {
        const int j = mi * 4 + r;
#pragma unroll
        for (int ni = 0; ni < 2; ++ni) {
          const float d = fmaf(-2.f, C[mi][ni][r], cs[ni]);
          const int code = cg * 128 + w * 32 + ni * 16 + l15;
          if (d < best[j]) { best[j] = d; bidx[j] = code; }  // codes ascending
        }
      }
  }

  // ---- cross-lane argmin (over the 16 l15 code-columns) ----
#pragma unroll
  for (int m = 1; m <= 8; m <<= 1) {
#pragma unroll
    for (int j = 0; j < 16; ++j) {
      const float od = __shfl_xor(best[j], m, 64);
      const int oi = __shfl_xor(bidx[j], m, 64);
      if (od < best[j] || (od == best[j] && oi < bidx[j])) { best[j] = od; bidx[j] = oi; }
    }
  }

  // ---- cross-wave merge via LDS (overlay sB; all sB reads are done) ----
  float* md = (float*)sB;                      // [4][64]
  int* mim = (int*)((char*)sB + 1024);         // [4][64]
  int* skid = (int*)((char*)sB + 2048);        // [64]
  float* red = (float*)((char*)sB + 2304);     // [4]
  __syncthreads();                             // everyone done reading sB
  if (l15 == 0) {
#pragma unroll
    for (int mi = 0; mi < 4; ++mi)
#pragma unroll
      for (int r = 0; r < 4; ++r) {
        const int row = mi * 16 + quad * 4 + r;
        md[w * 64 + row] = best[mi * 4 + r];
        mim[w * 64 + row] = bidx[mi * 4 + r];
      }
  }
  __syncthreads();
  if (t < 64) {
    float bd = md[t];
    int bi = mim[t];
#pragma unroll
    for (int ww = 1; ww < 4; ++ww) {
      const float od = md[ww * 64 + t];
      const int oi = mim[ww * 64 + t];
      if (od < bd || (od == bd && oi < bi)) { bd = od; bi = oi; }
    }
    skid[t] = bi;
  }
  __syncthreads();

  // ---- epilogue: gather + straight-through out + masked MSE ----
  const int wv = w;
  const int dg = lane;
  const int b = row0 >> 11;
  float acc = 0.f;
#pragma unroll
  for (int i = 0; i < 16; ++i) {
    const int r = wv * 16 + i;
    const size_t row = row0 + r;
    const int k = skid[r];
    const float4 q = ((const float4*)cb)[k * (DIM / 4) + dg];
    const float4 x = ((const float4*)feat)[row * (DIM / 4) + dg];
    float4 o;
    o.x = x.x + (q.x - x.x);
    o.y = x.y + (q.y - x.y);
    o.z = x.z + (q.z - x.z);
    o.w = x.w + (q.w - x.w);
    ((float4*)outq)[row * (DIM / 4) + dg] = o;
    const float m = mask[row];
    const float dx = x.x - q.x, dy = x.y - q.y, dz = x.z - q.z, dw = x.w - q.w;
    acc = fmaf(m, dx * dx + dy * dy + dz * dz + dw * dw, acc);
  }
  acc = wave_reduce_sum(acc);
  if (lane == 0) red[wv] = acc;
  __syncthreads();
  if (t == 0) atomicAdd(&lsum[b], red[0] + red[1] + red[2] + red[3]);
}

__global__ void k_final(const float* __restrict__ lsum,
                        const float* __restrict__ denom,
                        float* __restrict__ outl) {
  const int t = threadIdx.x;
  if (t < BATCH) {
    const float v = lsum[t] / denom[t];
    outl[t] = v;          // quant_loss
    outl[BATCH + t] = v;  // commit_loss (identical in forward)
  }
}

extern "C" void kernel_launch(void* const* d_in, const int* in_sizes, int n_in,
                              void* d_out, int out_size, void* d_ws, size_t ws_size,
                              hipStream_t stream) {
  const float* feat = (const float*)d_in[0];  // [16,2048,256]
  const float* mask = (const float*)d_in[1];  // [16,2048]
  const float* cb   = (const float*)d_in[2];  // [1024,256]
  float* out = (float*)d_out;

  char* p = (char*)d_ws;
  short8* bbuf = (short8*)p;                 p += (size_t)64 * 1024 * 16;    // 1.05 MB
  float* cbsq  = (float*)p;                  p += NCODES * 4;
  float* denom = (float*)p;                  p += BATCH * 4;
  float* lsum  = (float*)p;

  k_prep<<<64 + 16, NTHR, 0, stream>>>(cb, mask, bbuf, cbsq, denom, lsum);
  k_mega<<<NROWS / 64, NTHR, 0, stream>>>(bbuf, cbsq, feat, cb, mask, out, lsum);
  k_final<<<1, 64, 0, stream>>>(lsum, denom, out + (size_t)NROWS * DIM);
}

// Round 11
// 138.585 us; speedup vs baseline: 1.3424x; 1.0599x over previous
//
#include <hip/hip_runtime.h>

#define DIM    256
#define NCODES 1024
#define BATCH  16
#define SEQ    2048
#define NROWS  (BATCH * SEQ)   // 32768
#define NTHR   256

typedef short short8 __attribute__((ext_vector_type(8)));
typedef float f32x4 __attribute__((ext_vector_type(4)));

__device__ __forceinline__ float wave_reduce_sum(float s) {
#pragma unroll
  for (int off = 32; off > 0; off >>= 1) s += __shfl_down(s, off, 64);
  return s;
}

// round-to-nearest-even float -> bf16 (raw short)
__device__ __forceinline__ short f2bf(float f) {
  unsigned u = __builtin_bit_cast(unsigned, f);
  u = (u + 0x7fff + ((u >> 16) & 1)) >> 16;
  return (short)u;
}
__device__ __forceinline__ float bf2f(short s) {
  unsigned u = ((unsigned)(unsigned short)s) << 16;
  return __builtin_bit_cast(float, u);
}

// ---- small prep: B pack (blocks 0..63), mask/denom (64..79) ----
// bbuf: [(g128*8+s)*1024 + ((nb8*2+reg)*4+kgl)*16 + m] short8
//   code = g128*128 + nb8*16 + m ; dims = s*32 + kgl*8 + j ; reg0=hi reg1=lo
__global__ __launch_bounds__(NTHR) void k_prep(const float* __restrict__ cb,
                                               const float* __restrict__ mask,
                                               short8* __restrict__ bbuf,
                                               float* __restrict__ cbsq,
                                               float* __restrict__ denom,
                                               float* __restrict__ lsum) {
  const int bid = blockIdx.x;
  const int t = threadIdx.x;
  __shared__ float tile[16 * 257];
  if (bid < 64) {
    // ---- prep B: 16 codes per block ----
    const int nb = bid;
    const float* src = cb + (size_t)nb * 16 * DIM;
#pragma unroll
    for (int i = 0; i < 16; ++i) tile[i * 257 + t] = src[i * DIM + t];
    __syncthreads();
#pragma unroll
    for (int it = 0; it < 4; ++it) {
      const int idx = it * NTHR + t;
      const int kg = idx >> 4;
      const int m = idx & 15;
      const int reg = kg >> 5;
      const int sk = kg & 31;
      const int sg = sk >> 2;
      const int kgl = sk & 3;
      short8 v;
#pragma unroll
      for (int j = 0; j < 8; ++j) {
        const float w = tile[m * 257 + sk * 8 + j];
        const short h = f2bf(w);
        v[j] = reg ? f2bf(w - bf2f(h)) : h;
      }
      bbuf[(size_t)((nb >> 3) * 8 + sg) * 1024 +
           (((nb & 7) * 2 + reg) * 4 + kgl) * 16 + m] = v;
    }
    if (t < 16) {
      float s2 = 0.f;
      for (int c = 0; c < DIM; ++c) { const float w = tile[t * 257 + c]; s2 = fmaf(w, w, s2); }
      cbsq[nb * 16 + t] = s2;
    }
  } else {
    // ---- mask sums + zero loss accumulators ----
    const int b = bid - 64;
    float s = 0.f;
    for (int i = t; i < SEQ; i += NTHR) s += mask[b * SEQ + i];
    s = wave_reduce_sum(s);
    __shared__ float red[NTHR / 64];
    if ((t & 63) == 0) red[t >> 6] = s;
    __syncthreads();
    if (t == 0) { denom[b] = red[0] + red[1] + red[2] + red[3]; lsum[b] = 0.f; }
  }
}

// ---- mega kernel: in-kernel A split-convert + score vs ALL 1024 codes +
//      block-local argmin + gather + straight-through + masked MSE ----
// R10 skeleton with the sB LDS round-trip DELETED: B's MFMA fragment
// address in bbuf is already lane-linear (chunk + w*256 + {0,64,128,192}
// + lane), so each wave loads its 4 fragments STRAIGHT from global into
// registers. bbuf (1 MB) is L2-resident as long as blocks stay roughly
// in-phase; one __syncthreads per phase fences the loads into their phase
// (R9/R10 proved the barrier keeps FETCH at 36 MB; R8 without barriers
// exploded to 257 MB). Per phase: 1 barrier + 4 global loads/wave +
// 8 A ds_reads/wave + 24 MFMAs/wave. No ds_write, no drain, no sB.
// LDS = 64 KB sA + ~2.3 KB merge scratch -> 2 blocks/CU.
// Fragment values and MFMA order identical to R10 -> bit-exact.
__global__ __launch_bounds__(NTHR, 2) void k_mega(const short8* __restrict__ bbuf,
                                                  const float* __restrict__ cbsq,
                                                  const float* __restrict__ feat,
                                                  const float* __restrict__ cb,
                                                  const float* __restrict__ mask,
                                                  float* __restrict__ outq,
                                                  float* __restrict__ lsum) {
  __shared__ short8 sA[4096];  // 64 KB: slot = s*512 + mi*128 + reg*64 + kgl*16 + m
  __shared__ float md[256];    // merge scratch
  __shared__ int mim[256];
  __shared__ int skid[64];
  __shared__ float red[4];
  const int t = threadIdx.x;
  const int w = t >> 6;
  const int lane = t & 63;
  const int l15 = lane & 15;
  const int quad = lane >> 4;
  const int blk = blockIdx.x;        // 512 blocks x 64 rows
  const int row0 = blk * 64;

  // ---- phase 0: convert this block's 64 rows f32 -> hi/lo bf16 into sA ----
  {
    const float4* __restrict__ fsrc = (const float4*)feat;
    const int mi = w;
    const int kgl = quad;            // == (t>>4)&3
    const int m = l15;
    const int row = row0 + mi * 16 + m;
#pragma unroll
    for (int s = 0; s < 8; ++s) {
      const size_t f4 = (size_t)row * 64 + s * 8 + kgl * 2;
      const float4 x0 = fsrc[f4];
      const float4 x1 = fsrc[f4 + 1];
      const float xs[8] = {x0.x, x0.y, x0.z, x0.w, x1.x, x1.y, x1.z, x1.w};
      short8 hi, lo;
#pragma unroll
      for (int j = 0; j < 8; ++j) {
        const short hh = f2bf(xs[j]);
        hi[j] = hh;
        lo[j] = f2bf(xs[j] - bf2f(hh));
      }
      sA[s * 512 + mi * 128 + 0 * 64 + kgl * 16 + m] = hi;   // conflict-free b128
      sA[s * 512 + mi * 128 + 1 * 64 + kgl * 16 + m] = lo;
    }
  }

  float best[16];
  int bidx[16];
#pragma unroll
  for (int j = 0; j < 16; ++j) { best[j] = 3.4e38f; bidx[j] = 0; }

#pragma unroll 1
  for (int cg = 0; cg < 8; ++cg) {   // 128-code groups
    f32x4 C[4][2];
#pragma unroll
    for (int mi = 0; mi < 4; ++mi)
#pragma unroll
      for (int ni = 0; ni < 2; ++ni) C[mi][ni] = (f32x4)0.f;

#pragma unroll
    for (int s = 0; s < 8; ++s) {
      __syncthreads();               // phase fence: keeps waves/blocks in-phase
                                     // (drains sA conversion at cg=0,s=0)
      // ---- B fragments straight from global (L2-resident, lane-linear) ----
      const short8* gB = bbuf + ((size_t)cg * 8 + s) * 1024 + w * 256 + lane;
      const short8 bh0 = gB[0];
      const short8 bl0 = gB[64];
      const short8 bh1 = gB[128];
      const short8 bl1 = gB[192];
      // ---- A fragments from LDS ----
      short8 ah[4], al[4];
#pragma unroll
      for (int mi = 0; mi < 4; ++mi) {
        ah[mi] = sA[s * 512 + mi * 128 + quad * 16 + l15];
        al[mi] = sA[s * 512 + mi * 128 + 64 + quad * 16 + l15];
      }
#pragma unroll
      for (int mi = 0; mi < 4; ++mi) {
        C[mi][0] = __builtin_amdgcn_mfma_f32_16x16x32_bf16(ah[mi], bh0, C[mi][0], 0, 0, 0);
        C[mi][1] = __builtin_amdgcn_mfma_f32_16x16x32_bf16(ah[mi], bh1, C[mi][1], 0, 0, 0);
      }
#pragma unroll
      for (int mi = 0; mi < 4; ++mi) {
        C[mi][0] = __builtin_amdgcn_mfma_f32_16x16x32_bf16(al[mi], bh0, C[mi][0], 0, 0, 0);
        C[mi][1] = __builtin_amdgcn_mfma_f32_16x16x32_bf16(al[mi], bh1, C[mi][1], 0, 0, 0);
      }
#pragma unroll
      for (int mi = 0; mi < 4; ++mi) {
        C[mi][0] = __builtin_amdgcn_mfma_f32_16x16x32_bf16(ah[mi], bl0, C[mi][0], 0, 0, 0);
        C[mi][1] = __builtin_amdgcn_mfma_f32_16x16x32_bf16(ah[mi], bl1, C[mi][1], 0, 0, 0);
      }
    }

    // ---- fold this code-group into per-lane running argmin ----
    float cs[2];
#pragma unroll
    for (int ni = 0; ni < 2; ++ni) cs[ni] = cbsq[cg * 128 + w * 32 + ni * 16 + l15];
#pragma unroll
    for (int mi = 0; mi < 4; ++mi)
#pragma unroll
      for (int r = 0; r < 4; ++r) {
        const int j = mi * 4 + r;
#pragma unroll
        for (int ni = 0; ni < 2; ++ni) {
          const float d = fmaf(-2.f, C[mi][ni][r], cs[ni]);
          const int code = cg * 128 + w * 32 + ni * 16 + l15;
          if (d < best[j]) { best[j] = d; bidx[j] = code; }  // codes ascending
        }
      }
  }

  // ---- cross-lane argmin (over the 16 l15 code-columns) ----
#pragma unroll
  for (int m = 1; m <= 8; m <<= 1) {
#pragma unroll
    for (int j = 0; j < 16; ++j) {
      const float od = __shfl_xor(best[j], m, 64);
      const int oi = __shfl_xor(bidx[j], m, 64);
      if (od < best[j] || (od == best[j] && oi < bidx[j])) { best[j] = od; bidx[j] = oi; }
    }
  }

  // ---- cross-wave merge via LDS scratch ----
  if (l15 == 0) {
#pragma unroll
    for (int mi = 0; mi < 4; ++mi)
#pragma unroll
      for (int r = 0; r < 4; ++r) {
        const int row = mi * 16 + quad * 4 + r;
        md[w * 64 + row] = best[mi * 4 + r];
        mim[w * 64 + row] = bidx[mi * 4 + r];
      }
  }
  __syncthreads();
  if (t < 64) {
    float bd = md[t];
    int bi = mim[t];
#pragma unroll
    for (int ww = 1; ww < 4; ++ww) {
      const float od = md[ww * 64 + t];
      const int oi = mim[ww * 64 + t];
      if (od < bd || (od == bd && oi < bi)) { bd = od; bi = oi; }
    }
    skid[t] = bi;
  }
  __syncthreads();

  // ---- epilogue: gather + straight-through out + masked MSE ----
  const int wv = w;
  const int dg = lane;
  const int b = row0 >> 11;
  float acc = 0.f;
#pragma unroll
  for (int i = 0; i < 16; ++i) {
    const int r = wv * 16 + i;
    const size_t row = row0 + r;
    const int k = skid[r];
    const float4 q = ((const float4*)cb)[k * (DIM / 4) + dg];
    const float4 x = ((const float4*)feat)[row * (DIM / 4) + dg];
    float4 o;
    o.x = x.x + (q.x - x.x);
    o.y = x.y + (q.y - x.y);
    o.z = x.z + (q.z - x.z);
    o.w = x.w + (q.w - x.w);
    ((float4*)outq)[row * (DIM / 4) + dg] = o;
    const float m = mask[row];
    const float dx = x.x - q.x, dy = x.y - q.y, dz = x.z - q.z, dw = x.w - q.w;
    acc = fmaf(m, dx * dx + dy * dy + dz * dz + dw * dw, acc);
  }
  acc = wave_reduce_sum(acc);
  if (lane == 0) red[wv] = acc;
  __syncthreads();
  if (t == 0) atomicAdd(&lsum[b], red[0] + red[1] + red[2] + red[3]);
}

__global__ void k_final(const float* __restrict__ lsum,
                        const float* __restrict__ denom,
                        float* __restrict__ outl) {
  const int t = threadIdx.x;
  if (t < BATCH) {
    const float v = lsum[t] / denom[t];
    outl[t] = v;          // quant_loss
    outl[BATCH + t] = v;  // commit_loss (identical in forward)
  }
}

extern "C" void kernel_launch(void* const* d_in, const int* in_sizes, int n_in,
                              void* d_out, int out_size, void* d_ws, size_t ws_size,
                              hipStream_t stream) {
  const float* feat = (const float*)d_in[0];  // [16,2048,256]
  const float* mask = (const float*)d_in[1];  // [16,2048]
  const float* cb   = (const float*)d_in[2];  // [1024,256]
  float* out = (float*)d_out;

  char* p = (char*)d_ws;
  short8* bbuf = (short8*)p;                 p += (size_t)64 * 1024 * 16;    // 1.05 MB
  float* cbsq  = (float*)p;                  p += NCODES * 4;
  float* denom = (float*)p;                  p += BATCH * 4;
  float* lsum  = (float*)p;

  k_prep<<<64 + 16, NTHR, 0, stream>>>(cb, mask, bbuf, cbsq, denom, lsum);
  k_mega<<<NROWS / 64, NTHR, 0, stream>>>(bbuf, cbsq, feat, cb, mask, out, lsum);
  k_final<<<1, 64, 0, stream>>>(lsum, denom, out + (size_t)NROWS * DIM);
}

// Round 12
// 134.132 us; speedup vs baseline: 1.3870x; 1.0332x over previous
//
#include <hip/hip_runtime.h>

#define DIM    256
#define NCODES 1024
#define BATCH  16
#define SEQ    2048
#define NROWS  (BATCH * SEQ)   // 32768
#define NTHR   256

typedef short short8 __attribute__((ext_vector_type(8)));
typedef float f32x4 __attribute__((ext_vector_type(4)));

__device__ __forceinline__ float wave_reduce_sum(float s) {
#pragma unroll
  for (int off = 32; off > 0; off >>= 1) s += __shfl_down(s, off, 64);
  return s;
}

// round-to-nearest-even float -> bf16 (raw short)
__device__ __forceinline__ short f2bf(float f) {
  unsigned u = __builtin_bit_cast(unsigned, f);
  u = (u + 0x7fff + ((u >> 16) & 1)) >> 16;
  return (short)u;
}
__device__ __forceinline__ float bf2f(short s) {
  unsigned u = ((unsigned)(unsigned short)s) << 16;
  return __builtin_bit_cast(float, u);
}

// ---- small prep: B pack (blocks 0..63), mask/denom (64..79) ----
// bbuf: [(g128*8+s)*1024 + ((nb8*2+reg)*4+kgl)*16 + m] short8
//   code = g128*128 + nb8*16 + m ; dims = s*32 + kgl*8 + j ; reg0=hi reg1=lo
__global__ __launch_bounds__(NTHR) void k_prep(const float* __restrict__ cb,
                                               const float* __restrict__ mask,
                                               short8* __restrict__ bbuf,
                                               float* __restrict__ cbsq,
                                               float* __restrict__ denom,
                                               float* __restrict__ lsum) {
  const int bid = blockIdx.x;
  const int t = threadIdx.x;
  __shared__ float tile[16 * 257];
  if (bid < 64) {
    // ---- prep B: 16 codes per block ----
    const int nb = bid;
    const float* src = cb + (size_t)nb * 16 * DIM;
#pragma unroll
    for (int i = 0; i < 16; ++i) tile[i * 257 + t] = src[i * DIM + t];
    __syncthreads();
#pragma unroll
    for (int it = 0; it < 4; ++it) {
      const int idx = it * NTHR + t;
      const int kg = idx >> 4;
      const int m = idx & 15;
      const int reg = kg >> 5;
      const int sk = kg & 31;
      const int sg = sk >> 2;
      const int kgl = sk & 3;
      short8 v;
#pragma unroll
      for (int j = 0; j < 8; ++j) {
        const float w = tile[m * 257 + sk * 8 + j];
        const short h = f2bf(w);
        v[j] = reg ? f2bf(w - bf2f(h)) : h;
      }
      bbuf[(size_t)((nb >> 3) * 8 + sg) * 1024 +
           (((nb & 7) * 2 + reg) * 4 + kgl) * 16 + m] = v;
    }
    if (t < 16) {
      float s2 = 0.f;
      for (int c = 0; c < DIM; ++c) { const float w = tile[t * 257 + c]; s2 = fmaf(w, w, s2); }
      cbsq[nb * 16 + t] = s2;
    }
  } else {
    // ---- mask sums + zero loss accumulators ----
    const int b = bid - 64;
    float s = 0.f;
    for (int i = t; i < SEQ; i += NTHR) s += mask[b * SEQ + i];
    s = wave_reduce_sum(s);
    __shared__ float red[NTHR / 64];
    if ((t & 63) == 0) red[t >> 6] = s;
    __syncthreads();
    if (t == 0) { denom[b] = red[0] + red[1] + red[2] + red[3]; lsum[b] = 0.f; }
  }
}

// ---- mega kernel: in-kernel A split-convert + score vs ALL 1024 codes +
//      block-local argmin + gather + straight-through + masked MSE ----
// R11 skeleton widened to ni=4: each wave covers 64 rows x 64 codes per
// phase (48 MFMAs between barriers instead of 24; 32 phases instead of 64).
// B fragments straight from bbuf (L2-resident, lane-linear); one barrier
// per phase keeps blocks phase-coherent (FETCH stays ~36 MB).
// Per phase/wave: 8 B global loads + 8 A ds_reads + 48 MFMAs + 1 barrier.
// LDS = 64 KB sA + ~2.3 KB merge scratch -> 2 blocks/CU.
// Per-(row,code) MFMA chain (hh,lh,hl per s, s ascending) and per-lane
// ascending-code argmin fold preserved -> bit-exact.
__global__ __launch_bounds__(NTHR, 2) void k_mega(const short8* __restrict__ bbuf,
                                                  const float* __restrict__ cbsq,
                                                  const float* __restrict__ feat,
                                                  const float* __restrict__ cb,
                                                  const float* __restrict__ mask,
                                                  float* __restrict__ outq,
                                                  float* __restrict__ lsum) {
  __shared__ short8 sA[4096];  // 64 KB: slot = s*512 + mi*128 + reg*64 + kgl*16 + m
  __shared__ float md[256];    // merge scratch
  __shared__ int mim[256];
  __shared__ int skid[64];
  __shared__ float red[4];
  const int t = threadIdx.x;
  const int w = t >> 6;
  const int lane = t & 63;
  const int l15 = lane & 15;
  const int quad = lane >> 4;
  const int blk = blockIdx.x;        // 512 blocks x 64 rows
  const int row0 = blk * 64;

  // ---- phase 0: convert this block's 64 rows f32 -> hi/lo bf16 into sA ----
  {
    const float4* __restrict__ fsrc = (const float4*)feat;
    const int mi = w;
    const int kgl = quad;            // == (t>>4)&3
    const int m = l15;
    const int row = row0 + mi * 16 + m;
#pragma unroll
    for (int s = 0; s < 8; ++s) {
      const size_t f4 = (size_t)row * 64 + s * 8 + kgl * 2;
      const float4 x0 = fsrc[f4];
      const float4 x1 = fsrc[f4 + 1];
      const float xs[8] = {x0.x, x0.y, x0.z, x0.w, x1.x, x1.y, x1.z, x1.w};
      short8 hi, lo;
#pragma unroll
      for (int j = 0; j < 8; ++j) {
        const short hh = f2bf(xs[j]);
        hi[j] = hh;
        lo[j] = f2bf(xs[j] - bf2f(hh));
      }
      sA[s * 512 + mi * 128 + 0 * 64 + kgl * 16 + m] = hi;   // conflict-free b128
      sA[s * 512 + mi * 128 + 1 * 64 + kgl * 16 + m] = lo;
    }
  }

  float best[16];
  int bidx[16];
#pragma unroll
  for (int j = 0; j < 16; ++j) { best[j] = 3.4e38f; bidx[j] = 0; }

#pragma unroll 1
  for (int cg2 = 0; cg2 < 4; ++cg2) {   // 256-code groups
    f32x4 C[4][4];
#pragma unroll
    for (int mi = 0; mi < 4; ++mi)
#pragma unroll
      for (int ni = 0; ni < 4; ++ni) C[mi][ni] = (f32x4)0.f;

#pragma unroll
    for (int s = 0; s < 8; ++s) {
      __syncthreads();               // phase fence: keeps waves/blocks in-phase
                                     // (drains sA conversion at cg2=0,s=0)
      // ---- B fragments straight from global (L2-resident, lane-linear) ----
      // wave w covers codes cg2*256 + w*64 .. +63:
      //   g128 = cg2*2 + (w>>1), nb8 = (w&1)*4 + ni
      const short8* gB = bbuf + ((size_t)((cg2 * 2 + (w >> 1)) * 8 + s)) * 1024 +
                         (w & 1) * 512 + lane;
      short8 bh[4], bl[4];
#pragma unroll
      for (int ni = 0; ni < 4; ++ni) {
        bh[ni] = gB[ni * 128];
        bl[ni] = gB[ni * 128 + 64];
      }
      // ---- A fragments from LDS ----
      short8 ah[4], al[4];
#pragma unroll
      for (int mi = 0; mi < 4; ++mi) {
        ah[mi] = sA[s * 512 + mi * 128 + quad * 16 + l15];
        al[mi] = sA[s * 512 + mi * 128 + 64 + quad * 16 + l15];
      }
#pragma unroll
      for (int mi = 0; mi < 4; ++mi)
#pragma unroll
        for (int ni = 0; ni < 4; ++ni)
          C[mi][ni] = __builtin_amdgcn_mfma_f32_16x16x32_bf16(ah[mi], bh[ni], C[mi][ni], 0, 0, 0);
#pragma unroll
      for (int mi = 0; mi < 4; ++mi)
#pragma unroll
        for (int ni = 0; ni < 4; ++ni)
          C[mi][ni] = __builtin_amdgcn_mfma_f32_16x16x32_bf16(al[mi], bh[ni], C[mi][ni], 0, 0, 0);
#pragma unroll
      for (int mi = 0; mi < 4; ++mi)
#pragma unroll
        for (int ni = 0; ni < 4; ++ni)
          C[mi][ni] = __builtin_amdgcn_mfma_f32_16x16x32_bf16(ah[mi], bl[ni], C[mi][ni], 0, 0, 0);
    }

    // ---- fold this 256-code group into per-lane running argmin ----
    float cs[4];
#pragma unroll
    for (int ni = 0; ni < 4; ++ni) cs[ni] = cbsq[cg2 * 256 + w * 64 + ni * 16 + l15];
#pragma unroll
    for (int mi = 0; mi < 4; ++mi)
#pragma unroll
      for (int r = 0; r < 4; ++r) {
        const int j = mi * 4 + r;
#pragma unroll
        for (int ni = 0; ni < 4; ++ni) {
          const float d = fmaf(-2.f, C[mi][ni][r], cs[ni]);
          const int code = cg2 * 256 + w * 64 + ni * 16 + l15;
          if (d < best[j]) { best[j] = d; bidx[j] = code; }  // codes ascending
        }
      }
  }

  // ---- cross-lane argmin (over the 16 l15 code-columns) ----
#pragma unroll
  for (int m = 1; m <= 8; m <<= 1) {
#pragma unroll
    for (int j = 0; j < 16; ++j) {
      const float od = __shfl_xor(best[j], m, 64);
      const int oi = __shfl_xor(bidx[j], m, 64);
      if (od < best[j] || (od == best[j] && oi < bidx[j])) { best[j] = od; bidx[j] = oi; }
    }
  }

  // ---- cross-wave merge via LDS scratch ----
  if (l15 == 0) {
#pragma unroll
    for (int mi = 0; mi < 4; ++mi)
#pragma unroll
      for (int r = 0; r < 4; ++r) {
        const int row = mi * 16 + quad * 4 + r;
        md[w * 64 + row] = best[mi * 4 + r];
        mim[w * 64 + row] = bidx[mi * 4 + r];
      }
  }
  __syncthreads();
  if (t < 64) {
    float bd = md[t];
    int bi = mim[t];
#pragma unroll
    for (int ww = 1; ww < 4; ++ww) {
      const float od = md[ww * 64 + t];
      const int oi = mim[ww * 64 + t];
      if (od < bd || (od == bd && oi < bi)) { bd = od; bi = oi; }
    }
    skid[t] = bi;
  }
  __syncthreads();

  // ---- epilogue: gather + straight-through out + masked MSE ----
  const int wv = w;
  const int dg = lane;
  const int b = row0 >> 11;
  float acc = 0.f;
#pragma unroll
  for (int i = 0; i < 16; ++i) {
    const int r = wv * 16 + i;
    const size_t row = row0 + r;
    const int k = skid[r];
    const float4 q = ((const float4*)cb)[k * (DIM / 4) + dg];
    const float4 x = ((const float4*)feat)[row * (DIM / 4) + dg];
    float4 o;
    o.x = x.x + (q.x - x.x);
    o.y = x.y + (q.y - x.y);
    o.z = x.z + (q.z - x.z);
    o.w = x.w + (q.w - x.w);
    ((float4*)outq)[row * (DIM / 4) + dg] = o;
    const float m = mask[row];
    const float dx = x.x - q.x, dy = x.y - q.y, dz = x.z - q.z, dw = x.w - q.w;
    acc = fmaf(m, dx * dx + dy * dy + dz * dz + dw * dw, acc);
  }
  acc = wave_reduce_sum(acc);
  if (lane == 0) red[wv] = acc;
  __syncthreads();
  if (t == 0) atomicAdd(&lsum[b], red[0] + red[1] + red[2] + red[3]);
}

__global__ void k_final(const float* __restrict__ lsum,
                        const float* __restrict__ denom,
                        float* __restrict__ outl) {
  const int t = threadIdx.x;
  if (t < BATCH) {
    const float v = lsum[t] / denom[t];
    outl[t] = v;          // quant_loss
    outl[BATCH + t] = v;  // commit_loss (identical in forward)
  }
}

extern "C" void kernel_launch(void* const* d_in, const int* in_sizes, int n_in,
                              void* d_out, int out_size, void* d_ws, size_t ws_size,
                              hipStream_t stream) {
  const float* feat = (const float*)d_in[0];  // [16,2048,256]
  const float* mask = (const float*)d_in[1];  // [16,2048]
  const float* cb   = (const float*)d_in[2];  // [1024,256]
  float* out = (float*)d_out;

  char* p = (char*)d_ws;
  short8* bbuf = (short8*)p;                 p += (size_t)64 * 1024 * 16;    // 1.05 MB
  float* cbsq  = (float*)p;                  p += NCODES * 4;
  float* denom = (float*)p;                  p += BATCH * 4;
  float* lsum  = (float*)p;

  k_prep<<<64 + 16, NTHR, 0, stream>>>(cb, mask, bbuf, cbsq, denom, lsum);
  k_mega<<<NROWS / 64, NTHR, 0, stream>>>(bbuf, cbsq, feat, cb, mask, out, lsum);
  k_final<<<1, 64, 0, stream>>>(lsum, denom, out + (size_t)NROWS * DIM);
}

// Round 13
// 134.100 us; speedup vs baseline: 1.3873x; 1.0002x over previous
//
#include <hip/hip_runtime.h>

#define DIM    256
#define NCODES 1024
#define BATCH  16
#define SEQ    2048
#define NROWS  (BATCH * SEQ)   // 32768
#define NTHR   256

typedef short short8 __attribute__((ext_vector_type(8)));
typedef float f32x4 __attribute__((ext_vector_type(4)));

__device__ __forceinline__ float wave_reduce_sum(float s) {
#pragma unroll
  for (int off = 32; off > 0; off >>= 1) s += __shfl_down(s, off, 64);
  return s;
}

// round-to-nearest-even float -> bf16 (raw short)
__device__ __forceinline__ short f2bf(float f) {
  unsigned u = __builtin_bit_cast(unsigned, f);
  u = (u + 0x7fff + ((u >> 16) & 1)) >> 16;
  return (short)u;
}
__device__ __forceinline__ float bf2f(short s) {
  unsigned u = ((unsigned)(unsigned short)s) << 16;
  return __builtin_bit_cast(float, u);
}

// ---- small prep: B pack (blocks 0..63), mask/denom (64..79) ----
// bbuf: [(g128*8+s)*1024 + ((nb8*2+reg)*4+kgl)*16 + m] short8
//   code = g128*128 + nb8*16 + m ; dims = s*32 + kgl*8 + j ; reg0=hi reg1=lo
__global__ __launch_bounds__(NTHR) void k_prep(const float* __restrict__ cb,
                                               const float* __restrict__ mask,
                                               short8* __restrict__ bbuf,
                                               float* __restrict__ cbsq,
                                               float* __restrict__ denom,
                                               float* __restrict__ lsum) {
  const int bid = blockIdx.x;
  const int t = threadIdx.x;
  __shared__ float tile[16 * 257];
  if (bid < 64) {
    // ---- prep B: 16 codes per block ----
    const int nb = bid;
    const float* src = cb + (size_t)nb * 16 * DIM;
#pragma unroll
    for (int i = 0; i < 16; ++i) tile[i * 257 + t] = src[i * DIM + t];
    __syncthreads();
#pragma unroll
    for (int it = 0; it < 4; ++it) {
      const int idx = it * NTHR + t;
      const int kg = idx >> 4;
      const int m = idx & 15;
      const int reg = kg >> 5;
      const int sk = kg & 31;
      const int sg = sk >> 2;
      const int kgl = sk & 3;
      short8 v;
#pragma unroll
      for (int j = 0; j < 8; ++j) {
        const float w = tile[m * 257 + sk * 8 + j];
        const short h = f2bf(w);
        v[j] = reg ? f2bf(w - bf2f(h)) : h;
      }
      bbuf[(size_t)((nb >> 3) * 8 + sg) * 1024 +
           (((nb & 7) * 2 + reg) * 4 + kgl) * 16 + m] = v;
    }
    if (t < 16) {
      float s2 = 0.f;
      for (int c = 0; c < DIM; ++c) { const float w = tile[t * 257 + c]; s2 = fmaf(w, w, s2); }
      cbsq[nb * 16 + t] = s2;
    }
  } else {
    // ---- mask sums + zero loss accumulators ----
    const int b = bid - 64;
    float s = 0.f;
    for (int i = t; i < SEQ; i += NTHR) s += mask[b * SEQ + i];
    s = wave_reduce_sum(s);
    __shared__ float red[NTHR / 64];
    if ((t & 63) == 0) red[t >> 6] = s;
    __syncthreads();
    if (t == 0) { denom[b] = red[0] + red[1] + red[2] + red[3]; lsum[b] = 0.f; }
  }
}

// ---- mega kernel: in-kernel A split-convert + score vs ALL 1024 codes +
//      block-local argmin + gather + straight-through + masked MSE ----
// R12 skeleton with the per-phase fence changed from __syncthreads (full
// memory fence: forbids hoisting next phase's B loads -> one exposed L2
// round-trip per phase) to RAW s_barrier (no fence). The main loop has NO
// LDS writes (sA read-only after conversion; B pure registers), so the
// fence semantics were never needed for correctness -- the barrier is only
// a pacing device that keeps waves/blocks phase-aligned so bbuf stays
// L2-resident (R8 proved no-pacing -> FETCH x7). With the raw barrier the
// compiler software-pipelines B loads across phases with counted vmcnt.
// Per phase/wave: 8 B global loads + 8 A ds_reads + 48 MFMAs + s_barrier.
// LDS = 64 KB sA + ~2.3 KB merge scratch -> 2 blocks/CU.
// Fragment values, MFMA chain order, argmin folds unchanged -> bit-exact.
__global__ __launch_bounds__(NTHR, 2) void k_mega(const short8* __restrict__ bbuf,
                                                  const float* __restrict__ cbsq,
                                                  const float* __restrict__ feat,
                                                  const float* __restrict__ cb,
                                                  const float* __restrict__ mask,
                                                  float* __restrict__ outq,
                                                  float* __restrict__ lsum) {
  __shared__ short8 sA[4096];  // 64 KB: slot = s*512 + mi*128 + reg*64 + kgl*16 + m
  __shared__ float md[256];    // merge scratch
  __shared__ int mim[256];
  __shared__ int skid[64];
  __shared__ float red[4];
  const int t = threadIdx.x;
  const int w = t >> 6;
  const int lane = t & 63;
  const int l15 = lane & 15;
  const int quad = lane >> 4;
  const int blk = blockIdx.x;        // 512 blocks x 64 rows
  const int row0 = blk * 64;

  // ---- phase 0: convert this block's 64 rows f32 -> hi/lo bf16 into sA ----
  {
    const float4* __restrict__ fsrc = (const float4*)feat;
    const int mi = w;
    const int kgl = quad;            // == (t>>4)&3
    const int m = l15;
    const int row = row0 + mi * 16 + m;
#pragma unroll
    for (int s = 0; s < 8; ++s) {
      const size_t f4 = (size_t)row * 64 + s * 8 + kgl * 2;
      const float4 x0 = fsrc[f4];
      const float4 x1 = fsrc[f4 + 1];
      const float xs[8] = {x0.x, x0.y, x0.z, x0.w, x1.x, x1.y, x1.z, x1.w};
      short8 hi, lo;
#pragma unroll
      for (int j = 0; j < 8; ++j) {
        const short hh = f2bf(xs[j]);
        hi[j] = hh;
        lo[j] = f2bf(xs[j] - bf2f(hh));
      }
      sA[s * 512 + mi * 128 + 0 * 64 + kgl * 16 + m] = hi;   // conflict-free b128
      sA[s * 512 + mi * 128 + 1 * 64 + kgl * 16 + m] = lo;
    }
  }
  __syncthreads();                   // the ONLY fencing barrier: sA ready

  float best[16];
  int bidx[16];
#pragma unroll
  for (int j = 0; j < 16; ++j) { best[j] = 3.4e38f; bidx[j] = 0; }

#pragma unroll 1
  for (int cg2 = 0; cg2 < 4; ++cg2) {   // 256-code groups
    f32x4 C[4][4];
#pragma unroll
    for (int mi = 0; mi < 4; ++mi)
#pragma unroll
      for (int ni = 0; ni < 4; ++ni) C[mi][ni] = (f32x4)0.f;

#pragma unroll
    for (int s = 0; s < 8; ++s) {
      __builtin_amdgcn_s_barrier();  // raw pacing barrier: no fence, loads
                                     // may stay in flight across it
      // ---- B fragments straight from global (L2-resident, lane-linear) ----
      // wave w covers codes cg2*256 + w*64 .. +63:
      //   g128 = cg2*2 + (w>>1), nb8 = (w&1)*4 + ni
      const short8* gB = bbuf + ((size_t)((cg2 * 2 + (w >> 1)) * 8 + s)) * 1024 +
                         (w & 1) * 512 + lane;
      short8 bh[4], bl[4];
#pragma unroll
      for (int ni = 0; ni < 4; ++ni) {
        bh[ni] = gB[ni * 128];
        bl[ni] = gB[ni * 128 + 64];
      }
      // ---- A fragments from LDS ----
      short8 ah[4], al[4];
#pragma unroll
      for (int mi = 0; mi < 4; ++mi) {
        ah[mi] = sA[s * 512 + mi * 128 + quad * 16 + l15];
        al[mi] = sA[s * 512 + mi * 128 + 64 + quad * 16 + l15];
      }
#pragma unroll
      for (int mi = 0; mi < 4; ++mi)
#pragma unroll
        for (int ni = 0; ni < 4; ++ni)
          C[mi][ni] = __builtin_amdgcn_mfma_f32_16x16x32_bf16(ah[mi], bh[ni], C[mi][ni], 0, 0, 0);
#pragma unroll
      for (int mi = 0; mi < 4; ++mi)
#pragma unroll
        for (int ni = 0; ni < 4; ++ni)
          C[mi][ni] = __builtin_amdgcn_mfma_f32_16x16x32_bf16(al[mi], bh[ni], C[mi][ni], 0, 0, 0);
#pragma unroll
      for (int mi = 0; mi < 4; ++mi)
#pragma unroll
        for (int ni = 0; ni < 4; ++ni)
          C[mi][ni] = __builtin_amdgcn_mfma_f32_16x16x32_bf16(ah[mi], bl[ni], C[mi][ni], 0, 0, 0);
    }

    // ---- fold this 256-code group into per-lane running argmin ----
    float cs[4];
#pragma unroll
    for (int ni = 0; ni < 4; ++ni) cs[ni] = cbsq[cg2 * 256 + w * 64 + ni * 16 + l15];
#pragma unroll
    for (int mi = 0; mi < 4; ++mi)
#pragma unroll
      for (int r = 0; r < 4; ++r) {
        const int j = mi * 4 + r;
#pragma unroll
        for (int ni = 0; ni < 4; ++ni) {
          const float d = fmaf(-2.f, C[mi][ni][r], cs[ni]);
          const int code = cg2 * 256 + w * 64 + ni * 16 + l15;
          if (d < best[j]) { best[j] = d; bidx[j] = code; }  // codes ascending
        }
      }
  }

  // ---- cross-lane argmin (over the 16 l15 code-columns) ----
#pragma unroll
  for (int m = 1; m <= 8; m <<= 1) {
#pragma unroll
    for (int j = 0; j < 16; ++j) {
      const float od = __shfl_xor(best[j], m, 64);
      const int oi = __shfl_xor(bidx[j], m, 64);
      if (od < best[j] || (od == best[j] && oi < bidx[j])) { best[j] = od; bidx[j] = oi; }
    }
  }

  // ---- cross-wave merge via LDS scratch ----
  if (l15 == 0) {
#pragma unroll
    for (int mi = 0; mi < 4; ++mi)
#pragma unroll
      for (int r = 0; r < 4; ++r) {
        const int row = mi * 16 + quad * 4 + r;
        md[w * 64 + row] = best[mi * 4 + r];
        mim[w * 64 + row] = bidx[mi * 4 + r];
      }
  }
  __syncthreads();
  if (t < 64) {
    float bd = md[t];
    int bi = mim[t];
#pragma unroll
    for (int ww = 1; ww < 4; ++ww) {
      const float od = md[ww * 64 + t];
      const int oi = mim[ww * 64 + t];
      if (od < bd || (od == bd && oi < bi)) { bd = od; bi = oi; }
    }
    skid[t] = bi;
  }
  __syncthreads();

  // ---- epilogue: gather + straight-through out + masked MSE ----
  const int wv = w;
  const int dg = lane;
  const int b = row0 >> 11;
  float acc = 0.f;
#pragma unroll
  for (int i = 0; i < 16; ++i) {
    const int r = wv * 16 + i;
    const size_t row = row0 + r;
    const int k = skid[r];
    const float4 q = ((const float4*)cb)[k * (DIM / 4) + dg];
    const float4 x = ((const float4*)feat)[row * (DIM / 4) + dg];
    float4 o;
    o.x = x.x + (q.x - x.x);
    o.y = x.y + (q.y - x.y);
    o.z = x.z + (q.z - x.z);
    o.w = x.w + (q.w - x.w);
    ((float4*)outq)[row * (DIM / 4) + dg] = o;
    const float m = mask[row];
    const float dx = x.x - q.x, dy = x.y - q.y, dz = x.z - q.z, dw = x.w - q.w;
    acc = fmaf(m, dx * dx + dy * dy + dz * dz + dw * dw, acc);
  }
  acc = wave_reduce_sum(acc);
  if (lane == 0) red[wv] = acc;
  __syncthreads();
  if (t == 0) atomicAdd(&lsum[b], red[0] + red[1] + red[2] + red[3]);
}

__global__ void k_final(const float* __restrict__ lsum,
                        const float* __restrict__ denom,
                        float* __restrict__ outl) {
  const int t = threadIdx.x;
  if (t < BATCH) {
    const float v = lsum[t] / denom[t];
    outl[t] = v;          // quant_loss
    outl[BATCH + t] = v;  // commit_loss (identical in forward)
  }
}

extern "C" void kernel_launch(void* const* d_in, const int* in_sizes, int n_in,
                              void* d_out, int out_size, void* d_ws, size_t ws_size,
                              hipStream_t stream) {
  const float* feat = (const float*)d_in[0];  // [16,2048,256]
  const float* mask = (const float*)d_in[1];  // [16,2048]
  const float* cb   = (const float*)d_in[2];  // [1024,256]
  float* out = (float*)d_out;

  char* p = (char*)d_ws;
  short8* bbuf = (short8*)p;                 p += (size_t)64 * 1024 * 16;    // 1.05 MB
  float* cbsq  = (float*)p;                  p += NCODES * 4;
  float* denom = (float*)p;                  p += BATCH * 4;
  float* lsum  = (float*)p;

  k_prep<<<64 + 16, NTHR, 0, stream>>>(cb, mask, bbuf, cbsq, denom, lsum);
  k_mega<<<NROWS / 64, NTHR, 0, stream>>>(bbuf, cbsq, feat, cb, mask, out, lsum);
  k_final<<<1, 64, 0, stream>>>(lsum, denom, out + (size_t)NROWS * DIM);
}